// Round 6
// baseline (2973.381 us; speedup 1.0000x reference)
//
#include <hip/hip_runtime.h>

// adder2d: out[b,f,l] = -sum_k |W[f,k] - P[b,k,l]|, P = 3x3/s1/p1 im2col of x.
// M=16*784=12544, N=F=128, K=1152. fp32 exact.
// R6: scalar-broadcast design. Wave = 64 m-lanes; 16 f's live in accumulators;
// W[f][k] chunks are wave-uniform -> s_load straight from the original layout
// (contiguous 18-k runs), used as the single SGPR operand of v_sub_f32.
// P loaded per-lane from global (L1-hot, 9-tap overlap), double-buffered in
// VGPRs. NO LDS in the hot loop. In-block k-split x4 (32 ch/wave), LDS only
// for the 3-round reduce tail. Grid 196x8 = 1568 blocks -> ~6 blocks/CU.

#define B_   16
#define C_   128
#define HH   28
#define WW   28
#define F_   128
#define L_   (HH * WW)          // 784
#define K_   (C_ * 9)           // 1152
#define M_   (B_ * L_)          // 12544 = 196 * 64
#define TFB  16                 // f per block (= accs per lane)
#define NW   4                  // waves per block (k-split)
#define CPWV (C_ / NW)          // 32 channels per wave
#define NCH  (CPWV / 2)         // 16 two-channel chunks per wave

__global__ __launch_bounds__(256, 6)
void adder2d_main(const float* __restrict__ x, const float* __restrict__ Wg,
                  float* __restrict__ out) {
    __shared__ float red[2][TFB * 64];     // reduce tail only: 8 KB

    const int t    = threadIdx.x;
    const int wid  = t >> 6;
    const int lane = t & 63;
    const int m0   = blockIdx.x * 64;
    const int f0   = blockIdx.y * TFB;

    // lane geometry (lane = m); m-groups may straddle images, bI is per-lane
    const int mG = m0 + lane;
    const int bI = mG / L_;
    const int lP = mG - bI * L_;
    const int ho = lP / WW;
    const int wo = lP - ho * WW;
    int roff[9];                            // tap offset within image plane, -1 = pad
    #pragma unroll
    for (int r = 0; r < 9; ++r) {
        const int kh = r / 3, kw = r - 3 * (r / 3);
        const int y = ho + kh - 1, xx = wo + kw - 1;
        roff[r] = (y >= 0 && y < HH && xx >= 0 && xx < WW) ? (y * WW + xx) : -1;
    }
    const float* xb = x + (size_t)bI * (C_ * L_);
    const int c0 = wid * CPWV;              // this wave's channel range

    float acc[TFB];
    #pragma unroll
    for (int j = 0; j < TFB; ++j) acc[j] = 0.f;

    float pA[18], pB[18];

    // load one 2-channel (18-k) P chunk into regs; pad lanes -> 0
    auto loadP = [&](float* dst, int cb) {
        #pragma unroll
        for (int cl = 0; cl < 2; ++cl)
            #pragma unroll
            for (int r = 0; r < 9; ++r) {
                float v = 0.f;
                if (roff[r] >= 0) v = xb[(cb + cl) * L_ + roff[r]];
                dst[cl * 9 + r] = v;
            }
    };
    // 16 f's x 18 k's: W chunk via wave-uniform scalar loads (contiguous 18 floats)
    auto compute = [&](const float* p, int cb) {
        #pragma unroll
        for (int j = 0; j < TFB; ++j) {
            const float* wr = Wg + (size_t)(f0 + j) * K_ + cb * 9;
            #pragma unroll
            for (int i = 0; i < 18; ++i)
                acc[j] += __builtin_fabsf(wr[i] - p[i]);
        }
    };

    loadP(pA, c0);
    for (int ch = 0; ch < NCH; ch += 2) {
        {   // even chunk: prefetch next into pB, compute on pA
            const int cb = c0 + ch * 2;
            const int cn = (ch + 1 < NCH) ? (cb + 2) : cb;       // clamp, in-bounds
            loadP(pB, cn);
            compute(pA, cb);
        }
        {   // odd chunk: prefetch next into pA, compute on pB
            const int cb = c0 + (ch + 1) * 2;
            const int cn = (ch + 2 < NCH) ? (cb + 2) : c0;       // clamp, in-bounds
            loadP(pA, cn);
            compute(pB, cb);
        }
    }

    // ---- cross-wave reduce: 4 -> 2 -> 1
    __syncthreads();
    if (wid >= 2) {
        float* R = red[wid - 2];
        #pragma unroll
        for (int j = 0; j < TFB; ++j) R[j * 64 + lane] = acc[j];
    }
    __syncthreads();
    if (wid < 2) {
        const float* R = red[wid];
        #pragma unroll
        for (int j = 0; j < TFB; ++j) acc[j] += R[j * 64 + lane];
    }
    __syncthreads();
    if (wid == 1) {
        #pragma unroll
        for (int j = 0; j < TFB; ++j) red[0][j * 64 + lane] = acc[j];
    }
    __syncthreads();
    if (wid == 0) {
        #pragma unroll
        for (int j = 0; j < TFB; ++j) {
            const float v = acc[j] + red[0][j * 64 + lane];
            out[(size_t)(bI * F_ + f0 + j) * L_ + lP] = -v;   // coalesced b32 across lanes
        }
    }
}

extern "C" void kernel_launch(void* const* d_in, const int* in_sizes, int n_in,
                              void* d_out, int out_size, void* d_ws, size_t ws_size,
                              hipStream_t stream) {
    const float* x = (const float*)d_in[0];   // [16,128,28,28]
    const float* W = (const float*)d_in[1];   // [128,128,3,3]
    float* out = (float*)d_out;               // [16,128,28,28]

    dim3 grid(M_ / 64, F_ / TFB);             // (196, 8) = 1568 blocks of 256
    adder2d_main<<<grid, 256, 0, stream>>>(x, W, out);
}

// Round 7
// 289.297 us; speedup vs baseline: 10.2780x; 10.2780x over previous
//
#include <hip/hip_runtime.h>

// adder2d: out[b,f,l] = -sum_k |W[f,k] - P[b,k,l]|, P = 3x3/s1/p1 im2col of x.
// M=16*784=12544, N=F=128, K=1152. fp32 exact.
// R7: 8x8 micro/lane (LDS demand 64 B/cyc/CU < 85 achievable -> VALU-bound,
// model validated against R2's measured 67%). Tile = 64m x 128f per
// 128-thread block (2 waves, spill-free ~90 VGPR per R4 evidence).
// K-split x8 across blockIdx.z -> 1568 blocks, ALL resident (~10 blocks/CU).
// Partials to d_ws slabs + R2-proven combine kernel. No atomics.

#define B_   16
#define C_   128
#define HH   28
#define WW   28
#define F_   128
#define L_   (HH * WW)          // 784
#define K_   (C_ * 9)           // 1152
#define M_   (B_ * L_)          // 12544 = 196 * 64
#define TMB  64                 // m per block
#define LP   68                 // P row pitch (words)
#define LW   132                // W row pitch (words)
#define KC   18                 // k-rows per chunk (2 channels)
#define SLAB (B_ * F_ * L_)     // 1,605,632 floats per partial slab
#define SMF  (KC * LP + KC * LW)       // 3600 staging floats
#define SMSZ ((SMF > 4096) ? SMF : 4096)  // union with 4096-float reduce buf

__global__ __launch_bounds__(128, 2)
void adder2d_main(const float* __restrict__ x, const float* __restrict__ Wg,
                  float* __restrict__ dst, int nch2, int direct) {
    __shared__ float sm[SMSZ];
    float* Pl = sm;                 // [KC][LP]
    float* Wl = sm + KC * LP;       // [KC][LW]

    const int t    = threadIdx.x;
    const int wid  = t >> 6;        // 0..1
    const int lane = t & 63;
    const int tx   = lane & 7;      // m-group (8 m's)
    const int ty   = lane >> 3;     // f-group (8 f's), 0..7 -> with wid: 0..15
    const int fy   = wid * 8 + ty;  // 16 f-groups cover 128 f
    const int m0   = blockIdx.x * TMB;
    const int c0   = blockIdx.z * nch2 * 2;   // first channel of this split

    // ---- P staging geometry: col = t&63 (m), this thread covers channel-half
    // rh = t>>6 of each 2-channel chunk, taps r=0..8.
    const int colP = t & 63;
    const int rh   = t >> 6;        // 0..1 = channel within chunk
    const int mGs  = m0 + colP;
    const int bIs  = mGs / L_;
    const int lPs  = mGs - bIs * L_;
    const int hos  = lPs / WW;
    const int wos  = lPs - hos * WW;
    int roff[9];
    #pragma unroll
    for (int r = 0; r < 9; ++r) {
        const int kh = r / 3, kw = r - 3 * (r / 3);
        const int y = hos + kh - 1, xx = wos + kw - 1;
        roff[r] = (y >= 0 && y < HH && xx >= 0 && xx < WW) ? (y * WW + xx) : -1;
    }
    const float* xb = x + (size_t)bIs * (C_ * L_);
    // ---- W staging: thread t owns f-row t, 18 consecutive k per chunk
    const float* wrow = Wg + (size_t)t * K_ + c0 * 9;

    float acc[8][8];
    #pragma unroll
    for (int i = 0; i < 8; ++i)
        #pragma unroll
        for (int j = 0; j < 8; ++j) acc[i][j] = 0.0f;

    for (int ch = 0; ch < nch2; ++ch) {
        __syncthreads();            // WAR: previous reads done
        // stage P: channel (c0 + 2ch + rh), 9 taps, col = colP
        const float* xc = xb + (c0 + 2 * ch + rh) * L_;
        #pragma unroll
        for (int r = 0; r < 9; ++r) {
            float v = 0.0f;
            if (roff[r] >= 0) v = xc[roff[r]];
            Pl[(rh * 9 + r) * LP + colP] = v;
        }
        // stage W: f-row t, k-window [c0*9 + 18ch, +18)
        const float* wc = wrow + ch * KC;
        #pragma unroll
        for (int i = 0; i < KC; ++i) Wl[i * LW + t] = wc[i];
        __syncthreads();
        // hot loop: 18 k-steps x (4 ds_read_b128 [fixed offsets] + 128 VALU)
        #pragma unroll
        for (int k = 0; k < KC; ++k) {
            const float4 p0 = *(const float4*)&Pl[k * LP + tx * 8];
            const float4 p1 = *(const float4*)&Pl[k * LP + tx * 8 + 4];
            const float4 q0 = *(const float4*)&Wl[k * LW + fy * 8];
            const float4 q1 = *(const float4*)&Wl[k * LW + fy * 8 + 4];
            const float pv[8] = {p0.x, p0.y, p0.z, p0.w, p1.x, p1.y, p1.z, p1.w};
            const float wv[8] = {q0.x, q0.y, q0.z, q0.w, q1.x, q1.y, q1.z, q1.w};
            #pragma unroll
            for (int i = 0; i < 8; ++i)
                #pragma unroll
                for (int j = 0; j < 8; ++j)
                    acc[i][j] += __builtin_fabsf(pv[i] - wv[j]);
        }
    }

    // ---- store: each (lane, fy) owns an 8x8 patch; waves write disjoint f's.
    // 8-m group never straddles an image (8 | 784).
    const int mo = m0 + tx * 8;
    const int bo = mo / L_;
    const int lo = mo - bo * L_;
    float* slab = direct ? dst : dst + (size_t)blockIdx.z * SLAB;
    const float sgn = direct ? -1.0f : 1.0f;
    float* ob = slab + (size_t)bo * (F_ * L_) + lo;
    #pragma unroll
    for (int j = 0; j < 8; ++j) {
        float* orow = ob + (size_t)(fy * 8 + j) * L_;
        *(float4*)&orow[0] = make_float4(sgn * acc[0][j], sgn * acc[1][j],
                                         sgn * acc[2][j], sgn * acc[3][j]);
        *(float4*)&orow[4] = make_float4(sgn * acc[4][j], sgn * acc[5][j],
                                         sgn * acc[6][j], sgn * acc[7][j]);
    }
}

__global__ __launch_bounds__(256)
void adder2d_combine(const float* __restrict__ ws, float* __restrict__ out, int nslab) {
    const int i = blockIdx.x * 256 + threadIdx.x;     // float4 index
    float4 s = make_float4(0.f, 0.f, 0.f, 0.f);
    for (int z = 0; z < nslab; ++z) {
        const float4 p = ((const float4*)(ws + (size_t)z * SLAB))[i];
        s.x += p.x; s.y += p.y; s.z += p.z; s.w += p.w;
    }
    ((float4*)out)[i] = make_float4(-s.x, -s.y, -s.z, -s.w);
}

extern "C" void kernel_launch(void* const* d_in, const int* in_sizes, int n_in,
                              void* d_out, int out_size, void* d_ws, size_t ws_size,
                              hipStream_t stream) {
    const float* x = (const float*)d_in[0];   // [16,128,28,28]
    const float* W = (const float*)d_in[1];   // [128,128,3,3]
    float* out = (float*)d_out;               // [16,128,28,28]
    float* ws  = (float*)d_ws;

    int Z = 1;
    if (ws_size >= (size_t)8 * SLAB * sizeof(float)) Z = 8;        // ~51.4 MB
    else if (ws_size >= (size_t)4 * SLAB * sizeof(float)) Z = 4;   // ~25.7 MB

    const int nch2 = (C_ / Z) / 2;            // 2-channel chunks per block
    if (Z > 1) {
        dim3 grid(M_ / TMB, 1, Z);            // (196, 1, Z) -> 1568 blocks @ Z=8
        adder2d_main<<<grid, 128, 0, stream>>>(x, W, ws, nch2, 0);
        adder2d_combine<<<SLAB / 4 / 256, 256, 0, stream>>>(ws, out, Z);
    } else {
        dim3 grid(M_ / TMB, 1, 1);
        adder2d_main<<<grid, 128, 0, stream>>>(x, W, out, nch2, 1);
    }
}